// Round 3
// baseline (995.926 us; speedup 1.0000x reference)
//
#include <hip/hip_runtime.h>

// Problem constants (reference: BATCH=65536, SEQ_LEN=1024, M=32, DEGREE=7 -> D=8)
#define MM 32
#define DD 8
#define LL 1024
#define NBATCH 65536
#define NBLOCKS 1024   // 4 blocks/CU on 256 CUs -> 4 waves/SIMD for latency hiding

// Folded solve weights: Wt[i][d][j] = (Ginv_i * V_i^T)[d][j].  32 KB, recomputed
// every kernel_launch (graph-capture safe), L2-resident for the main kernel.
// Module-global instead of d_ws to avoid any ws_size assumption.
__device__ float g_Wt[MM * DD * MM];

// ---------------------------------------------------------------------------
// Kernel 1: build Chebyshev Vandermonde per row-group i, form 8x8 Gram in
// fp64, Gauss-Jordan invert, fold: Wt[i][d][j] = sum_e Ginv[d][e] * V[j][e].
// One block per i (32 blocks), 64 threads.
// ---------------------------------------------------------------------------
__global__ void precompute_w_kernel(const float* __restrict__ tg) {
    const int i = blockIdx.x;
    const int t = threadIdx.x;

    __shared__ float  V[MM][DD];        // V[j][e]
    __shared__ double A[DD][2 * DD];    // Gauss-Jordan augmented [G | I]

    // times[i][j] = tg[j*32 + i]
    if (t < MM) {
        float tt = tg[t * MM + i];
        float c0 = 1.0f, c1 = tt;
        V[t][0] = c0;
        V[t][1] = c1;
        for (int e = 2; e < DD; ++e) {
            float c2 = 2.0f * tt * c1 - c0;
            V[t][e] = c2;
            c0 = c1; c1 = c2;
        }
    }
    __syncthreads();

    // Gram matrix in fp64: thread t -> (d,e)
    {
        int d = t >> 3, e = t & 7;
        double s = 0.0;
        for (int j = 0; j < MM; ++j) s += (double)V[j][d] * (double)V[j][e];
        A[d][e] = s;
        A[d][DD + e] = (d == e) ? 1.0 : 0.0;
    }
    __syncthreads();

    // Gauss-Jordan (SPD, no pivoting needed), single thread, fp64, in LDS.
    if (t == 0) {
        for (int p = 0; p < DD; ++p) {
            double inv = 1.0 / A[p][p];
            for (int c = p; c < 2 * DD; ++c) A[p][c] *= inv;
            for (int r2 = 0; r2 < DD; ++r2) {
                if (r2 == p) continue;
                double f = A[r2][p];
                for (int c = p; c < 2 * DD; ++c) A[r2][c] -= f * A[p][c];
            }
        }
    }
    __syncthreads();

    // Wt[i][d][j] = sum_e Ginv[d][e] * V[j][e]
    for (int k = t; k < DD * MM; k += 64) {
        int d = k >> 5;
        int j = k & 31;
        double s = 0.0;
        for (int e = 0; e < DD; ++e) s += A[d][DD + e] * (double)V[j][e];
        g_Wt[(i * DD + d) * MM + j] = (float)s;
    }
}

// ---------------------------------------------------------------------------
// Kernel 2: apply W to every batch row.
// Wave = one row per iteration. lane -> (i4 = lane>>3, d = lane&7).
// Lane loads float4 covering i = 4*i4 .. 4*i4+3 at column j: byte offset
// j*128 + i4*16 -> the wave's 8 distinct 16-B segments are contiguous 128 B
// (8-way same-address duplication across d is a free broadcast).
// coeffs[r, 4*i4+ii, dd] = sum_j wr[ii][j] * xv[ii]
// ---------------------------------------------------------------------------
__global__ __launch_bounds__(256, 2) void poly_apply_kernel(
        const float* __restrict__ x,
        float* __restrict__ out) {
    const int lane = threadIdx.x & 63;
    const int wv   = threadIdx.x >> 6;
    const int i4   = lane >> 3;
    const int dd   = lane & 7;
    const int gw   = blockIdx.x * 4 + wv;              // 0 .. NBLOCKS*4-1
    const int ROWS_PER_WAVE = NBATCH / (NBLOCKS * 4);  // 16

    // Preload weights into registers: wr[ii][j] = Wt[4*i4+ii][dd][j] (128 VGPRs)
    float wr[4][32];
    const float4* wt4 = (const float4*)g_Wt;
#pragma unroll
    for (int ii = 0; ii < 4; ++ii) {
        const float4* wp = wt4 + ((size_t)((4 * i4 + ii) * DD + dd)) * (MM / 4);
#pragma unroll
        for (int jq = 0; jq < 8; ++jq) {
            float4 w4 = wp[jq];
            wr[ii][4 * jq + 0] = w4.x;
            wr[ii][4 * jq + 1] = w4.y;
            wr[ii][4 * jq + 2] = w4.z;
            wr[ii][4 * jq + 3] = w4.w;
        }
    }

    const int r0 = gw * ROWS_PER_WAVE;
    for (int r = r0; r < r0 + ROWS_PER_WAVE; ++r) {
        const float4* xr = (const float4*)(x + (size_t)r * LL) + i4;
        float a0 = 0.f, a1 = 0.f, a2 = 0.f, a3 = 0.f;
#pragma unroll
        for (int j = 0; j < 32; ++j) {
            float4 xv = xr[j * 8];   // one base addr + imm offset j*128 (<4096)
            a0 = fmaf(wr[0][j], xv.x, a0);
            a1 = fmaf(wr[1][j], xv.y, a1);
            a2 = fmaf(wr[2][j], xv.z, a2);
            a3 = fmaf(wr[3][j], xv.w, a3);
        }
        float* orow = out + (size_t)r * (MM * DD) + i4 * 32 + dd;
        orow[0]  = a0;   // i = 4*i4 + 0
        orow[8]  = a1;   // i = 4*i4 + 1
        orow[16] = a2;   // i = 4*i4 + 2
        orow[24] = a3;   // i = 4*i4 + 3
    }
}

extern "C" void kernel_launch(void* const* d_in, const int* in_sizes, int n_in,
                              void* d_out, int out_size, void* d_ws, size_t ws_size,
                              hipStream_t stream) {
    const float* x  = (const float*)d_in[0];   // [65536, 1024] f32
    const float* tg = (const float*)d_in[1];   // [1024] f32
    float* out = (float*)d_out;                // [65536, 32, 8] f32
    (void)d_ws; (void)ws_size;

    precompute_w_kernel<<<32, 64, 0, stream>>>(tg);
    poly_apply_kernel<<<NBLOCKS, 256, 0, stream>>>(x, out);
}

// Round 5
// 473.634 us; speedup vs baseline: 2.1027x; 2.1027x over previous
//
#include <hip/hip_runtime.h>

// Problem constants (reference: BATCH=65536, SEQ_LEN=1024, M=32, DEGREE=7 -> D=8)
#define MM 32
#define DD 8
#define LL 1024
#define NBATCH 65536
#define NBLOCKS 1024
#define ROWS_PER_BLOCK (NBATCH / NBLOCKS)  // 64
#define NITERS (ROWS_PER_BLOCK / 4)        // 16 iterations of 4 rows per block

// Folded solve weights: Wt[i][d][j] = (Ginv_i * V_i^T)[d][j]. 32 KB, recomputed
// every launch (graph-capture safe), L2-resident for the main kernel.
__device__ float g_Wt[MM * DD * MM];

// ---------------------------------------------------------------------------
// Kernel 1: build Chebyshev Vandermonde per row-group i, form 8x8 Gram in
// fp64, Gauss-Jordan invert, fold: Wt[i][d][j] = sum_e Ginv[d][e] * V[j][e].
// ---------------------------------------------------------------------------
__global__ void precompute_w_kernel(const float* __restrict__ tg) {
    const int i = blockIdx.x;
    const int t = threadIdx.x;

    __shared__ float  V[MM][DD];        // V[j][e]
    __shared__ double A[DD][2 * DD];    // Gauss-Jordan augmented [G | I]

    if (t < MM) {
        float tt = tg[t * MM + i];      // times[i][j] = tg[j*32 + i]
        float c0 = 1.0f, c1 = tt;
        V[t][0] = c0;
        V[t][1] = c1;
        for (int e = 2; e < DD; ++e) {
            float c2 = 2.0f * tt * c1 - c0;
            V[t][e] = c2;
            c0 = c1; c1 = c2;
        }
    }
    __syncthreads();

    {
        int d = t >> 3, e = t & 7;
        double s = 0.0;
        for (int j = 0; j < MM; ++j) s += (double)V[j][d] * (double)V[j][e];
        A[d][e] = s;
        A[d][DD + e] = (d == e) ? 1.0 : 0.0;
    }
    __syncthreads();

    if (t == 0) {
        for (int p = 0; p < DD; ++p) {
            double inv = 1.0 / A[p][p];
            for (int c = p; c < 2 * DD; ++c) A[p][c] *= inv;
            for (int r2 = 0; r2 < DD; ++r2) {
                if (r2 == p) continue;
                double f = A[r2][p];
                for (int c = p; c < 2 * DD; ++c) A[r2][c] -= f * A[p][c];
            }
        }
    }
    __syncthreads();

    for (int k = t; k < DD * MM; k += 64) {
        int d = k >> 5;
        int j = k & 31;
        double s = 0.0;
        for (int e = 0; e < DD; ++e) s += A[d][DD + e] * (double)V[j][e];
        g_Wt[(i * DD + d) * MM + j] = (float)s;
    }
}

// ---------------------------------------------------------------------------
// Kernel 2: wave = one row; lane = (i4 = lane>>3, dd = lane&7).
// Reads: per j one dwordx4 per lane at byte j*128 + i4*16 (wave covers a
// contiguous 128-B line; 8-lane same-address duplication is a free
// broadcast within the single memory instruction).
// Weights live in registers (launch_bounds(256,1) -> VGPR cap 512, no
// spill; asm pin defeats rematerialization).
// Writes: staged in padded LDS, then written back as full 128-B lines
// (256 threads x float4 covering 4 rows).
// ---------------------------------------------------------------------------
__global__ __launch_bounds__(256, 1) void poly_apply_kernel(
        const float* __restrict__ x,
        float* __restrict__ out) {
    // OL: 4 rows staged; per row: i4-stride 36 words (2-way/free ds_write banks)
    __shared__ float OL[4 * 288 + 16];

    const int t    = threadIdx.x;
    const int lane = t & 63;
    const int w    = t >> 6;        // wave 0..3
    const int i4   = lane >> 3;     // 0..7
    const int dd   = lane & 7;      // 0..7

    // Preload weights into registers: wr[ii][j] = Wt[4*i4+ii][dd][j] (128 VGPRs)
    float wr[4][32];
    const float4* wt4 = (const float4*)g_Wt;
#pragma unroll
    for (int ii = 0; ii < 4; ++ii) {
        const float4* wp = wt4 + (size_t)((4 * i4 + ii) * DD + dd) * (MM / 4);
#pragma unroll
        for (int jq = 0; jq < 8; ++jq) {
            float4 w4 = wp[jq];
            wr[ii][4 * jq + 0] = w4.x;
            wr[ii][4 * jq + 1] = w4.y;
            wr[ii][4 * jq + 2] = w4.z;
            wr[ii][4 * jq + 3] = w4.w;
        }
    }
    // Pin weights in VGPRs: opaque asm prevents spill/rematerialize-in-loop.
#pragma unroll
    for (int ii = 0; ii < 4; ++ii)
#pragma unroll
        for (int j = 0; j < 32; ++j)
            asm volatile("" : "+v"(wr[ii][j]));

    const int r0 = blockIdx.x * ROWS_PER_BLOCK;

    for (int itr = 0; itr < NITERS; ++itr) {
        const int rA = r0 + itr * 4;

        // ---- compute: wave w handles row rA + w ----
        {
            const float4* xr = (const float4*)(x + (size_t)(rA + w) * LL) + i4;
            float a0 = 0.f, a1 = 0.f, a2 = 0.f, a3 = 0.f;
#pragma unroll
            for (int j = 0; j < 32; ++j) {
                float4 xv = xr[j * 8];   // byte offset j*128 (imm), +i4*16 in base
                a0 = fmaf(wr[0][j], xv.x, a0);
                a1 = fmaf(wr[1][j], xv.y, a1);
                a2 = fmaf(wr[2][j], xv.z, a2);
                a3 = fmaf(wr[3][j], xv.w, a3);
            }
            // stage to LDS: word = w*288 + i4*36 + ii*8 + dd  (banks 2-way, free)
            float* op = OL + w * 288 + i4 * 36 + dd;
            op[0]  = a0;   // ii = 0 -> i = 4*i4+0
            op[8]  = a1;   // ii = 1
            op[16] = a2;   // ii = 2
            op[24] = a3;   // ii = 3
        }
        __syncthreads();

        // ---- writeback: 256 threads x float4 = 4 rows, full 128-B lines ----
        {
            const int rl = t >> 6;   // row-local 0..3 (== wave)
            const int q  = t & 63;   // float4 index within 1-KB row
            const int iq = q >> 1;   // i = 0..31
            const float4 v = *(const float4*)(OL + rl * 288 + (iq >> 2) * 36 +
                                              (iq & 3) * 8 + 4 * (q & 1));
            ((float4*)(out + (size_t)(rA + rl) * 256))[q] = v;
        }
        __syncthreads();   // protect OL before next iteration's stores
    }
}

extern "C" void kernel_launch(void* const* d_in, const int* in_sizes, int n_in,
                              void* d_out, int out_size, void* d_ws, size_t ws_size,
                              hipStream_t stream) {
    const float* x  = (const float*)d_in[0];   // [65536, 1024] f32
    const float* tg = (const float*)d_in[1];   // [1024] f32
    float* out = (float*)d_out;                // [65536, 32, 8] f32
    (void)d_ws; (void)ws_size;

    precompute_w_kernel<<<32, 64, 0, stream>>>(tg);
    poly_apply_kernel<<<NBLOCKS, 256, 0, stream>>>(x, out);
}

// Round 7
// 401.506 us; speedup vs baseline: 2.4805x; 1.1796x over previous
//
#include <hip/hip_runtime.h>

// Problem constants (reference: BATCH=65536, SEQ_LEN=1024, M=32, DEGREE=7 -> D=8)
#define MM 32
#define DD 8
#define LL 1024
#define NBATCH 65536
#define NBLK 2048
#define RPB (NBATCH / NBLK)   // 32 rows per block

// Folded solve weights: Wt[i][d][j] = (Ginv_i * V_i^T)[d][j]. 32 KB, recomputed
// every launch (graph-capture safe), L2-resident for the main kernel.
// Layout: g_Wt[(i*8+d)*32 + j] so thread t=(i*8+d) reads a linear 128-B slab.
__device__ float g_Wt[MM * DD * MM];

// ---------------------------------------------------------------------------
// Kernel 1: build Chebyshev Vandermonde per row-group i, form 8x8 Gram in
// fp64, Gauss-Jordan invert, fold: Wt[i][d][j] = sum_e Ginv[d][e] * V[j][e].
// ---------------------------------------------------------------------------
__global__ void precompute_w_kernel(const float* __restrict__ tg) {
    const int i = blockIdx.x;
    const int t = threadIdx.x;

    __shared__ float  V[MM][DD];        // V[j][e]
    __shared__ double A[DD][2 * DD];    // Gauss-Jordan augmented [G | I]

    if (t < MM) {
        float tt = tg[t * MM + i];      // times[i][j] = tg[j*32 + i]
        float c0 = 1.0f, c1 = tt;
        V[t][0] = c0;
        V[t][1] = c1;
        for (int e = 2; e < DD; ++e) {
            float c2 = 2.0f * tt * c1 - c0;
            V[t][e] = c2;
            c0 = c1; c1 = c2;
        }
    }
    __syncthreads();

    {
        int d = t >> 3, e = t & 7;
        double s = 0.0;
        for (int j = 0; j < MM; ++j) s += (double)V[j][d] * (double)V[j][e];
        A[d][e] = s;
        A[d][DD + e] = (d == e) ? 1.0 : 0.0;
    }
    __syncthreads();

    if (t == 0) {
        for (int p = 0; p < DD; ++p) {
            double inv = 1.0 / A[p][p];
            for (int c = p; c < 2 * DD; ++c) A[p][c] *= inv;
            for (int r2 = 0; r2 < DD; ++r2) {
                if (r2 == p) continue;
                double f = A[r2][p];
                for (int c = p; c < 2 * DD; ++c) A[r2][c] -= f * A[p][c];
            }
        }
    }
    __syncthreads();

    for (int k = t; k < DD * MM; k += 64) {
        int d = k >> 5;
        int j = k & 31;
        double s = 0.0;
        for (int e = 0; e < DD; ++e) s += A[d][DD + e] * (double)V[j][e];
        g_Wt[(i * DD + d) * MM + j] = (float)s;
    }
}

// ---------------------------------------------------------------------------
// Kernel 2: thread t = (i = t>>3, d = t&7). Per row:
//   - 256 threads cooperatively load the whole 4-KB row as float4 (full
//     1-KB-per-wave-instr coalescing) into a padded LDS buffer (ping-pong).
//   - thread t computes out[r, i, d] = sum_j w[j] * xl[j*32+i] with its 32
//     register-resident weights; LDS reads are 8 banks x 8-way broadcast
//     (<=2-way per wave with the +4-words-per-32 pad -> free).
//   - store: 256 contiguous dwords per row (perfectly coalesced).
// Padded LDS index for element l: l + 4*(l>>5)  ->  (j,i) at j*36 + i.
// ---------------------------------------------------------------------------
__global__ __launch_bounds__(256, 4) void poly_apply_kernel(
        const float* __restrict__ x,
        float* __restrict__ out) {
    __shared__ float xl[2][1156];   // 36*32 = 1152 words (+4 slack), ~9.3 KB total

    const int t = threadIdx.x;      // 0..255
    const int i = t >> 3;           // 0..31

    // Preload this thread's 32 weights (128 B, linear): w[j] = Wt[i][d][j]
    float w[32];
    {
        const float4* wp = (const float4*)g_Wt + t * 8;
#pragma unroll
        for (int q = 0; q < 8; ++q) {
            float4 v4 = wp[q];
            w[4 * q + 0] = v4.x;
            w[4 * q + 1] = v4.y;
            w[4 * q + 2] = v4.z;
            w[4 * q + 3] = v4.w;
        }
    }

    const int r0 = blockIdx.x * RPB;
    const int staddr = 4 * t + 4 * (t >> 3);                     // padded word addr for l=4t
    const float4* xr = (const float4*)(x + (size_t)r0 * LL) + t; // +256 float4 per row

    // Prologue: stage row 0, prefetch row 1 into regs.
    float4 v = xr[0];
    *(float4*)&xl[0][staddr] = v;
    v = xr[256];
    __syncthreads();

    for (int r = 0; r < RPB; ++r) {
        const int p = r & 1;
        // Write next row into the other buffer (prev-iter barrier protects it),
        // and issue the load for row r+2.
        if (r + 1 < RPB) *(float4*)&xl[p ^ 1][staddr] = v;
        if (r + 2 < RPB) v = xr[(size_t)(r + 2) * 256];

        // Compute from buffer p (row r).
        const float* xb = &xl[p][i];
        float acc = 0.f;
#pragma unroll
        for (int j = 0; j < 32; ++j)
            acc = fmaf(w[j], xb[j * 36], acc);
        out[(size_t)(r0 + r) * 256 + t] = acc;

        __syncthreads();   // buf p reads done; buf p^1 writes visible
    }
}

extern "C" void kernel_launch(void* const* d_in, const int* in_sizes, int n_in,
                              void* d_out, int out_size, void* d_ws, size_t ws_size,
                              hipStream_t stream) {
    const float* x  = (const float*)d_in[0];   // [65536, 1024] f32
    const float* tg = (const float*)d_in[1];   // [1024] f32
    float* out = (float*)d_out;                // [65536, 32, 8] f32
    (void)d_ws; (void)ws_size;

    precompute_w_kernel<<<32, 64, 0, stream>>>(tg);
    poly_apply_kernel<<<NBLK, 256, 0, stream>>>(x, out);
}